// Round 5
// baseline (11578.745 us; speedup 1.0000x reference)
//
#include <hip/hip_runtime.h>
#include <cstddef>
#include <cstdint>

// ---------------------------------------------------------------------------
// GATv2 x3 layers. R10 (GEMM/edge overlap via block-role fusion):
//  - R9 post-mortem: edge kernel is at its composite-BW roofline (1.39 GB
//    demand / 213us = 6.5 TB/s); depth-2 prefetch reverted (pure VALU cost).
//  - fused_step kernel: blocks [0,N) run edge for head-group g; next blocks
//    run MFMA GEMM for group g+1; (layer 3) last blocks pack W for group g+2.
//    No data deps within a launch; stream order carries cross-launch deps.
//    MFMA-bound GEMM hides under memory-bound edge (m114 co-scheduling).
//  - G halved (l2: 2, l3: 1) so the existing N x 2056-float slabs double-buffer
//    ping/pong without workspace growth.
//  - R8 kept: __expf, 2-op leaky, WIDTH=32 layer-1 edge, STASH for F4PT>=3.
//  - R7 kept: XCD-chunked GEMM swizzle, global_load_lds, split-bf16 3-MFMA.
// ---------------------------------------------------------------------------

#define HEADS 32
#define SLOPE_ATT 0.2f
#define SLOPE_ACT 0.01f

typedef __bf16 bf16_t;
typedef __bf16 bf16x8 __attribute__((ext_vector_type(8)));
typedef float f32x16 __attribute__((ext_vector_type(16)));

#define GLDS16(gp, lp)                                                        \
  __builtin_amdgcn_global_load_lds(                                           \
      (const __attribute__((address_space(1))) void*)(gp),                    \
      (__attribute__((address_space(3))) void*)(lp), 16, 0, 0)

// ---------------- CSR build ----------------

__global__ __launch_bounds__(256) void init_counts_kernel(int* counts, int n) {
  int i = blockIdx.x * 256 + threadIdx.x;
  if (i < n) counts[i] = 1;  // self-loop
}

__global__ __launch_bounds__(256) void count_kernel(const int* __restrict__ dst, int* counts, int E) {
  int e = blockIdx.x * 256 + threadIdx.x;
  if (e < E) atomicAdd(&counts[dst[e]], 1);
}

__global__ __launch_bounds__(1024) void scan_kernel(const int* __restrict__ counts,
                                                    int* __restrict__ row_ptr,
                                                    int* __restrict__ cursor, int n) {
  __shared__ int sums[1024];
  int t = threadIdx.x;
  int per = (n + 1023) >> 10;
  int base = t * per;
  int s = 0;
  for (int i = 0; i < per; i++) { int idx = base + i; if (idx < n) s += counts[idx]; }
  sums[t] = s;
  __syncthreads();
  for (int off = 1; off < 1024; off <<= 1) {
    int v = (t >= off) ? sums[t - off] : 0;
    __syncthreads();
    sums[t] += v;
    __syncthreads();
  }
  int run = (t == 0) ? 0 : sums[t - 1];
  for (int i = 0; i < per; i++) {
    int idx = base + i;
    if (idx < n) { row_ptr[idx] = run; cursor[idx] = run; run += counts[idx]; }
  }
  if (t == 1023) row_ptr[n] = sums[1023];
}

__global__ __launch_bounds__(256) void scatter_edges_kernel(const int* __restrict__ ei, int* cursor,
                                                            int* col_src, int* col_dst, int E) {
  int e = blockIdx.x * 256 + threadIdx.x;
  if (e >= E) return;
  int src = ei[e], dst = ei[E + e];
  int pos = atomicAdd(&cursor[dst], 1);
  col_src[pos] = src;
  col_dst[pos] = dst;
}

__global__ __launch_bounds__(256) void scatter_loops_kernel(int* cursor, int* col_src, int* col_dst, int N) {
  int nid = blockIdx.x * 256 + threadIdx.x;
  if (nid >= N) return;
  int pos = atomicAdd(&cursor[nid], 1);
  col_src[pos] = nid;
  col_dst[pos] = nid;
}

// ---------------- split-bf16 pack: X[M,K] fp32 -> frag-major hi/lo ----------------

__global__ __launch_bounds__(256) void cvt_pack_kernel(const float* __restrict__ X,
                                                       bf16_t* __restrict__ hi,
                                                       bf16_t* __restrict__ lo,
                                                       int M, int Mpad, int K) {
  int t = blockIdx.x * 256 + threadIdx.x;
  int kchunks = K >> 3;
  int total = Mpad * kchunks;
  if (t >= total) return;
  int kc = t % kchunks;
  int m = t / kchunks;
  int mt = m >> 7, ml = m & 127;
  size_t o = ((size_t)(mt * kchunks + kc)) * 1024 + (size_t)ml * 8;
  float v[8];
  if (m < M) {
    float4 a = *(const float4*)(X + (size_t)m * K + kc * 8);
    float4 b = *(const float4*)(X + (size_t)m * K + kc * 8 + 4);
    v[0] = a.x; v[1] = a.y; v[2] = a.z; v[3] = a.w;
    v[4] = b.x; v[5] = b.y; v[6] = b.z; v[7] = b.w;
  } else {
#pragma unroll
    for (int i = 0; i < 8; i++) v[i] = 0.f;
  }
  union { bf16_t h[8]; float4 f; } uh, ul;
#pragma unroll
  for (int i = 0; i < 8; i++) {
    bf16_t h = (bf16_t)v[i];
    uh.h[i] = h;
    ul.h[i] = (bf16_t)(v[i] - (float)h);
  }
  *(float4*)(hi + o) = uh.f;
  *(float4*)(lo + o) = ul.f;
}

// ---------------- W pack body (G heads starting at h0) ----------------

__device__ __forceinline__ void pack_body(int pb, int perSide,
                                          const float* __restrict__ Wl,
                                          const float* __restrict__ Wr,
                                          bf16_t* __restrict__ hL, bf16_t* __restrict__ lL,
                                          bf16_t* __restrict__ hR, bf16_t* __restrict__ lR,
                                          int K, int C, int Npad, int ldW,
                                          int h0, int G) {
  int side = pb / perSide;
  int px = pb % perSide;
  const float* W = side ? Wr : Wl;
  bf16_t* Hi = side ? hR : hL;
  bf16_t* Lo = side ? lR : lL;
  int kchunks = K >> 3;
  int perhead = Npad * kchunks;
  int t = px * 256 + threadIdx.x;
  if (t >= G * perhead) return;
  int g = t / perhead, rem = t % perhead;
  int n = rem % Npad, kc = rem / Npad;
  int nt = n >> 7, nl = n & 127;
  size_t o = (size_t)g * Npad * K + ((size_t)(nt * kchunks + kc)) * 1024 + (size_t)nl * 8;
  int col0 = (h0 + g) * C;
  union { bf16_t hh[8]; float4 f; } uh, ul;
#pragma unroll
  for (int kk = 0; kk < 8; kk++) {
    int k = kc * 8 + kk;
    float v = (n < C) ? W[(size_t)k * ldW + col0 + n] : 0.f;
    bf16_t hv = (bf16_t)v;
    uh.hh[kk] = hv;
    ul.hh[kk] = (bf16_t)(v - (float)hv);
  }
  *(float4*)(Hi + o) = uh.f;
  *(float4*)(Lo + o) = ul.f;
}

__global__ __launch_bounds__(256) void pack_w_group_kernel(const float* __restrict__ Wl,
                                                           const float* __restrict__ Wr,
                                                           bf16_t* hL, bf16_t* lL,
                                                           bf16_t* hR, bf16_t* lR,
                                                           int K, int C, int Npad, int ldW,
                                                           int h0, int G) {
  pack_body(blockIdx.y * gridDim.x + blockIdx.x, gridDim.x,
            Wl, Wr, hL, lL, hR, lR, K, C, Npad, ldW, h0, G);
}

// ---------------- MFMA GEMM body (128x128 tile, XCD-chunked swizzle) ----------

__device__ __forceinline__ void gemm_body(int p, int gx, int gy, int gz,
                                          const bf16_t* __restrict__ Xh,
                                          const bf16_t* __restrict__ Xl,
                                          const bf16_t* __restrict__ BhL,
                                          const bf16_t* __restrict__ BlL,
                                          const bf16_t* __restrict__ BhR,
                                          const bf16_t* __restrict__ BlR,
                                          size_t bHeadStride,
                                          const float* __restrict__ bl,
                                          const float* __restrict__ br,
                                          float* __restrict__ outL,
                                          float* __restrict__ outR,
                                          size_t outHeadStride,
                                          int M, int K, int C, int h0,
                                          char* smem) {
  int nwg = gx * gy * gz;
  int q = nwg >> 3, r = nwg & 7;
  int xcd = p & 7, slot = p >> 3;
  int lid = (xcd < r ? xcd * (q + 1) : r * (q + 1) + (xcd - r) * q) + slot;
  const int NY = 8;
  int xzsz = gx * gz;
  int fullr = gy / NY;
  int lidf = fullr * NY * xzsz;
  int rectbase, ny, rem;
  if (lid < lidf) {
    int rect = lid / (NY * xzsz);
    rem = lid - rect * (NY * xzsz);
    rectbase = rect * NY;
    ny = NY;
  } else {
    rem = lid - lidf;
    rectbase = fullr * NY;
    ny = gy - rectbase;
  }
  int xz = rem / ny;
  int yl = rem - xz * ny;
  int bx = xz % gx;
  int bz = xz / gx;
  int by = rectbase + yl;

  int g = bz >> 1, side = bz & 1;
  const bf16_t* Bh = (side ? BhR : BhL) + (size_t)g * bHeadStride;
  const bf16_t* Bl = (side ? BlR : BlL) + (size_t)g * bHeadStride;
  const float* bias = side ? br : bl;
  float* out = (side ? outR : outL) + (size_t)g * outHeadStride;
  int col0 = (h0 + g) * C;

  bf16_t* AsH = (bf16_t*)smem;           // 8KB each
  bf16_t* AsL = (bf16_t*)(smem + 8192);
  bf16_t* BsH = (bf16_t*)(smem + 16384);
  bf16_t* BsL = (bf16_t*)(smem + 24576);

  int tid = threadIdx.x;
  int wave = tid >> 6, lane = tid & 63;
  int l31 = lane & 31, lhalf = lane >> 5;
  int mt = by;
  int ntb = bx * 128;
  int m0 = mt * 128;
  int kchunks = K >> 3;

  const bf16_t* Ah = Xh + (size_t)mt * K * 128;
  const bf16_t* Al = Xl + (size_t)mt * K * 128;
  const bf16_t* Bhp = Bh + (size_t)bx * kchunks * 1024;
  const bf16_t* Blp = Bl + (size_t)bx * kchunks * 1024;

  auto* asH3 = (__attribute__((address_space(3))) bf16_t*)AsH;
  auto* asL3 = (__attribute__((address_space(3))) bf16_t*)AsL;
  auto* bsH3 = (__attribute__((address_space(3))) bf16_t*)BsH;
  auto* bsL3 = (__attribute__((address_space(3))) bf16_t*)BsL;

  f32x16 acc[4];
#pragma unroll
  for (int i = 0; i < 4; i++)
#pragma unroll
    for (int rr = 0; rr < 16; rr++) acc[i][rr] = 0.f;

  for (int k0 = 0; k0 < K; k0 += 32) {
    int kc0 = k0 >> 3;
#pragma unroll
    for (int rr = 0; rr < 2; rr++) {
      int idx = tid + 256 * rr;
      size_t off = ((size_t)(kc0 + (idx >> 7))) * 1024 + (size_t)(idx & 127) * 8;
      int li = idx * 8;
      GLDS16(Ah + off, asH3 + li);
      GLDS16(Al + off, asL3 + li);
      GLDS16(Bhp + off, bsH3 + li);
      GLDS16(Blp + off, bsL3 + li);
    }
    __syncthreads();

#pragma unroll
    for (int s = 0; s < 2; s++) {
      int c = s * 2 + lhalf;
      int abase = (c * 128 + wave * 32 + l31) * 8;
      bf16x8 ah = *(const bf16x8*)(AsH + abase);
      bf16x8 al = *(const bf16x8*)(AsL + abase);
#pragma unroll
      for (int nt = 0; nt < 4; nt++) {
        int bbase = (c * 128 + nt * 32 + l31) * 8;
        bf16x8 bh = *(const bf16x8*)(BsH + bbase);
        bf16x8 blo = *(const bf16x8*)(BsL + bbase);
        acc[nt] = __builtin_amdgcn_mfma_f32_32x32x16_bf16(ah, bh, acc[nt], 0, 0, 0);
        acc[nt] = __builtin_amdgcn_mfma_f32_32x32x16_bf16(ah, blo, acc[nt], 0, 0, 0);
        acc[nt] = __builtin_amdgcn_mfma_f32_32x32x16_bf16(al, bh, acc[nt], 0, 0, 0);
      }
    }
    __syncthreads();
  }

#pragma unroll
  for (int nt = 0; nt < 4; nt++) {
    int n = ntb + nt * 32 + l31;
    if (n >= C) continue;
    float bv = bias[col0 + n];
#pragma unroll
    for (int rr = 0; rr < 16; rr++) {
      int row = (rr & 3) + 8 * (rr >> 2) + 4 * lhalf;
      int m = m0 + wave * 32 + row;
      if (m < M) out[(size_t)m * C + n] = acc[nt][rr] + bv;
    }
  }
}

// ---------------- fp32 GEMM (layer 1, K=4), grouped heads ----------------

#define BM 128
#define BN 128
#define BK 16
#define LDA (BM + 4)
#define LDB (BN + 4)

__global__ __launch_bounds__(256) void gemm128(const float* __restrict__ X,
                                               const float* __restrict__ Wl,
                                               const float* __restrict__ Wr,
                                               const float* __restrict__ bl,
                                               const float* __restrict__ br,
                                               float* __restrict__ outL,
                                               float* __restrict__ outR,
                                               int M, int K, int C, int ldW, int col0) {
  const float* W = blockIdx.z ? Wr : Wl;
  const float* bias = blockIdx.z ? br : bl;
  float* out = blockIdx.z ? outR : outL;

  __shared__ __align__(16) float As[BK][LDA];
  __shared__ __align__(16) float Bs[BK][LDB];

  int t = threadIdx.x;
  int tx = t & 15, ty = t >> 4;
  int m0 = blockIdx.y * BM, n0 = blockIdx.x * BN;

  float acc00[4][4] = {}, acc01[4][4] = {}, acc10[4][4] = {}, acc11[4][4] = {};

  for (int k0 = 0; k0 < K; k0 += BK) {
    {
      int kk = (t & 3) * 4;
#pragma unroll
      for (int p = 0; p < 2; p++) {
        int row = (t >> 2) + p * 64;
        int m = m0 + row;
        float4 v = make_float4(0.f, 0.f, 0.f, 0.f);
        if (m < M && (k0 + kk) < K)
          v = *(const float4*)(X + (size_t)m * K + k0 + kk);
        As[kk + 0][row] = v.x; As[kk + 1][row] = v.y;
        As[kk + 2][row] = v.z; As[kk + 3][row] = v.w;
      }
    }
    {
      int kk = t >> 4;
#pragma unroll
      for (int qq = 0; qq < 2; qq++) {
        int cn = (t & 15) * 4 + qq * 64;
        int n = n0 + cn;
        float4 v = make_float4(0.f, 0.f, 0.f, 0.f);
        if ((k0 + kk) < K && n + 3 < C)
          v = *(const float4*)(W + (size_t)(k0 + kk) * ldW + col0 + n);
        *(float4*)&Bs[kk][cn] = v;
      }
    }
    __syncthreads();

    int kmax = min(BK, K - k0);
    for (int kk = 0; kk < kmax; kk++) {
      float4 a0 = *(const float4*)&As[kk][ty * 4];
      float4 a1 = *(const float4*)&As[kk][64 + ty * 4];
      float4 b0 = *(const float4*)&Bs[kk][tx * 4];
      float4 b1 = *(const float4*)&Bs[kk][64 + tx * 4];
      float af0[4] = {a0.x, a0.y, a0.z, a0.w};
      float af1[4] = {a1.x, a1.y, a1.z, a1.w};
      float bf0[4] = {b0.x, b0.y, b0.z, b0.w};
      float bf1[4] = {b1.x, b1.y, b1.z, b1.w};
#pragma unroll
      for (int i = 0; i < 4; i++)
#pragma unroll
        for (int j = 0; j < 4; j++) {
          acc00[i][j] += af0[i] * bf0[j];
          acc01[i][j] += af0[i] * bf1[j];
          acc10[i][j] += af1[i] * bf0[j];
          acc11[i][j] += af1[i] * bf1[j];
        }
    }
    __syncthreads();
  }

#pragma unroll
  for (int ma = 0; ma < 2; ma++) {
#pragma unroll
    for (int i = 0; i < 4; i++) {
      int m = m0 + ma * 64 + ty * 4 + i;
      if (m >= M) continue;
#pragma unroll
      for (int nb = 0; nb < 2; nb++) {
        int n = n0 + nb * 64 + tx * 4;
        float (*blk)[4] = (ma == 0) ? ((nb == 0) ? acc00 : acc01)
                                    : ((nb == 0) ? acc10 : acc11);
        if (n + 3 < C) {
          float4 bv = *(const float4*)(bias + col0 + n);
          float4 o = make_float4(blk[i][0] + bv.x, blk[i][1] + bv.y,
                                 blk[i][2] + bv.z, blk[i][3] + bv.w);
          *(float4*)(out + (size_t)m * C + n) = o;
        }
      }
    }
  }
}

// ---------------- edge body (online softmax, R8 form) ----------------

template <int F4PT, int WIDTH>
__device__ __forceinline__ void edge_body(const int* __restrict__ row_ptr,
                                          const int* __restrict__ col_src,
                                          const float* __restrict__ xl,
                                          const float* __restrict__ xr,
                                          int ld4, size_t hstride4,
                                          const float* __restrict__ att,
                                          float* __restrict__ acc,
                                          int C, int head0, int G, int node,
                                          char* smem) {
  constexpr int NG = 256 / WIDTH;
  constexpr int ROW = F4PT * WIDTH;
  constexpr int ITER = (ROW + 255) / 256;
  constexpr bool STASH = (F4PT >= 3);
  float4 (*slab)[ROW] = (float4 (*)[ROW])smem;
  float* mred = (float*)(smem + (size_t)NG * ROW * 16);
  float* dred = mred + NG;
  int tid = threadIdx.x;
  int grp = tid / WIDTH, lane = tid % WIDTH;
  int C4 = C >> 2;
  int s = row_ptr[node], t = row_ptr[node + 1];

  float4 vtot[ITER];
#pragma unroll
  for (int it = 0; it < ITER; it++) vtot[it] = make_float4(0.f, 0.f, 0.f, 0.f);

  for (int g = 0; g < G; g++) {
    const float4* xlb = (const float4*)xl + (size_t)g * hstride4;
    const float4* xrp = (const float4*)xr + (size_t)g * hstride4 + (size_t)node * ld4;
    const float4* ap = (const float4*)(att + (size_t)g * C);

    float4 xr4[F4PT], a4[F4PT], o4[F4PT];
#pragma unroll
    for (int k = 0; k < F4PT; k++) {
      int c4 = k * WIDTH + lane;
      bool ok = (c4 < C4);
      xr4[k] = ok ? xrp[c4] : make_float4(0.f, 0.f, 0.f, 0.f);
      a4[k] = ok ? ap[c4] : make_float4(0.f, 0.f, 0.f, 0.f);
      o4[k] = make_float4(0.f, 0.f, 0.f, 0.f);
    }
    float m = -1e30f, den = 0.f;

    for (int j = s + grp; j < t; j += NG) {
      int src = col_src[j];
      const float4* xlp = xlb + (size_t)src * ld4;
      float4 x4[F4PT];
      float e = 0.f;
#pragma unroll
      for (int k = 0; k < F4PT; k++) {
        int c4 = k * WIDTH + lane;
        float4 xv = (c4 < C4) ? xlp[c4] : make_float4(0.f, 0.f, 0.f, 0.f);
        if constexpr (STASH) slab[grp][k * WIDTH + lane] = xv;
        else x4[k] = xv;
        float v;
        v = xv.x + xr4[k].x; v = fmaxf(v, SLOPE_ATT * v); e = fmaf(a4[k].x, v, e);
        v = xv.y + xr4[k].y; v = fmaxf(v, SLOPE_ATT * v); e = fmaf(a4[k].y, v, e);
        v = xv.z + xr4[k].z; v = fmaxf(v, SLOPE_ATT * v); e = fmaf(a4[k].z, v, e);
        v = xv.w + xr4[k].w; v = fmaxf(v, SLOPE_ATT * v); e = fmaf(a4[k].w, v, e);
      }
#pragma unroll
      for (int off = 1; off < WIDTH; off <<= 1) e += __shfl_xor(e, off, 64);

      if (e <= m) {  // group-uniform branch
        float p = __expf(e - m);
        den += p;
#pragma unroll
        for (int k = 0; k < F4PT; k++) {
          float4 xv;
          if constexpr (STASH) xv = slab[grp][k * WIDTH + lane];
          else xv = x4[k];
          o4[k].x = fmaf(p, xv.x, o4[k].x); o4[k].y = fmaf(p, xv.y, o4[k].y);
          o4[k].z = fmaf(p, xv.z, o4[k].z); o4[k].w = fmaf(p, xv.w, o4[k].w);
        }
      } else {
        float sc = __expf(m - e);  // m=-1e30 first time -> 0
        den = fmaf(den, sc, 1.f);
#pragma unroll
        for (int k = 0; k < F4PT; k++) {
          float4 xv;
          if constexpr (STASH) xv = slab[grp][k * WIDTH + lane];
          else xv = x4[k];
          o4[k].x = fmaf(o4[k].x, sc, xv.x); o4[k].y = fmaf(o4[k].y, sc, xv.y);
          o4[k].z = fmaf(o4[k].z, sc, xv.z); o4[k].w = fmaf(o4[k].w, sc, xv.w);
        }
        m = e;
      }
    }

    if (lane == 0) { mred[grp] = m; dred[grp] = den; }
    __syncthreads();
    float M2 = -1e30f;
#pragma unroll
    for (int i = 0; i < NG; i++) M2 = fmaxf(M2, mred[i]);
    float dtot = 0.f;
#pragma unroll
    for (int i = 0; i < NG; i++) dtot += dred[i] * __expf(mred[i] - M2);
    float f = __expf(m - M2);
#pragma unroll
    for (int k = 0; k < F4PT; k++) {
      float4 w4 = make_float4(o4[k].x * f, o4[k].y * f, o4[k].z * f, o4[k].w * f);
      slab[grp][k * WIDTH + lane] = w4;
    }
    __syncthreads();
    float inv = 1.0f / dtot;
#pragma unroll
    for (int it = 0; it < ITER; it++) {
      int c4 = tid + it * 256;
      if (c4 < ROW && c4 < C4) {
        float sx = 0.f, sy = 0.f, sz = 0.f, sw = 0.f;
#pragma unroll
        for (int i = 0; i < NG; i++) {
          float4 sv = slab[i][c4];
          sx += sv.x; sy += sv.y; sz += sv.z; sw += sv.w;
        }
        vtot[it].x = fmaf(sx, inv, vtot[it].x);
        vtot[it].y = fmaf(sy, inv, vtot[it].y);
        vtot[it].z = fmaf(sz, inv, vtot[it].z);
        vtot[it].w = fmaf(sw, inv, vtot[it].w);
      }
    }
    __syncthreads();  // slab reused next head
  }

  float4* accp = (float4*)(acc + (size_t)node * C);
#pragma unroll
  for (int it = 0; it < ITER; it++) {
    int c4 = tid + it * 256;
    if (c4 < ROW && c4 < C4) {
      if (head0 == 0) {
        accp[c4] = vtot[it];
      } else {
        float4 prev = accp[c4];
        accp[c4] = make_float4(prev.x + vtot[it].x, prev.y + vtot[it].y,
                               prev.z + vtot[it].z, prev.w + vtot[it].w);
      }
    }
  }
}

// ---------------- solo edge kernel (layer 1) ----------------

template <int F4PT, int WIDTH>
__global__ __launch_bounds__(256) void edge_solo(const int* __restrict__ row_ptr,
                                                 const int* __restrict__ col_src,
                                                 const float* __restrict__ xl,
                                                 const float* __restrict__ xr,
                                                 int ld4, size_t hstride4,
                                                 const float* __restrict__ att,
                                                 float* __restrict__ acc,
                                                 int C, int head0, int G) {
  constexpr int NG = 256 / WIDTH;
  constexpr int ROW = F4PT * WIDTH;
  __shared__ __align__(16) char smem[NG * ROW * 16 + 2 * NG * 4];
  edge_body<F4PT, WIDTH>(row_ptr, col_src, xl, xr, ld4, hstride4, att, acc,
                         C, head0, G, blockIdx.x, smem);
}

// ---------------- fused step: edge(g) || gemm(g+1) || pack(g+2) ----------------

template <int F4PT, int WIDTH>
__global__ __launch_bounds__(256) void fused_step(
    // edge (group g)
    const int* __restrict__ row_ptr, const int* __restrict__ col_src,
    const float* __restrict__ exl, const float* __restrict__ exr,
    int eld4, size_t ehstride4, const float* __restrict__ eatt,
    float* __restrict__ eacc, int Ce, int ehead0, int Ge, int nEdge,
    // gemm (group g+1); inactive if gx==0
    int gx, int gy, int gz,
    const bf16_t* __restrict__ Xh, const bf16_t* __restrict__ Xl,
    const bf16_t* __restrict__ BhL, const bf16_t* __restrict__ BlL,
    const bf16_t* __restrict__ BhR, const bf16_t* __restrict__ BlR,
    size_t bHeadStride, const float* __restrict__ gbl, const float* __restrict__ gbr,
    float* __restrict__ outL, float* __restrict__ outR, size_t outHeadStride,
    int M, int K, int Cg, int h0g,
    // pack (group g+2); inactive if packPerSide==0
    int packPerSide, const float* __restrict__ pWl, const float* __restrict__ pWr,
    bf16_t* __restrict__ phL, bf16_t* __restrict__ plL,
    bf16_t* __restrict__ phR, bf16_t* __restrict__ plR,
    int pK, int pC, int pNpad, int pldW, int ph0, int pG) {
  constexpr int NG = 256 / WIDTH;
  constexpr int ROW = F4PT * WIDTH;
  constexpr int EDGE_BYTES = NG * ROW * 16 + 2 * NG * 4;
  constexpr int LDS_SZ = (EDGE_BYTES > 32768) ? EDGE_BYTES : 32768;
  __shared__ __align__(16) char smem[LDS_SZ];

  int fb = blockIdx.x;
  if (fb < nEdge) {
    edge_body<F4PT, WIDTH>(row_ptr, col_src, exl, exr, eld4, ehstride4, eatt,
                           eacc, Ce, ehead0, Ge, fb, smem);
    return;
  }
  fb -= nEdge;
  int nwg = gx * gy * gz;
  if (fb < nwg) {
    gemm_body(fb, gx, gy, gz, Xh, Xl, BhL, BlL, BhR, BlR, bHeadStride,
              gbl, gbr, outL, outR, outHeadStride, M, K, Cg, h0g, smem);
    return;
  }
  fb -= nwg;
  if (packPerSide > 0 && fb < 2 * packPerSide) {
    pack_body(fb, packPerSide, pWl, pWr, phL, plL, phR, plR,
              pK, pC, pNpad, pldW, ph0, pG);
  }
}

// ---------------- finalize: mean over heads + bias (+ leaky relu) ----------------

__global__ __launch_bounds__(256) void finalize_kernel(const float* __restrict__ acc,
                                                       const float* __restrict__ bias,
                                                       float* __restrict__ out,
                                                       int total, int C, int apply_act) {
  int i = blockIdx.x * 256 + threadIdx.x;
  if (i >= total) return;
  int c = i % C;
  float v = acc[i] * (1.0f / 32.0f) + bias[c];
  if (apply_act) v = fmaxf(v, SLOPE_ACT * v);
  out[i] = v;
}

// ---------------- host ----------------

static inline size_t align16(size_t x) { return (x + 15) & ~size_t(15); }

extern "C" void kernel_launch(void* const* d_in, const int* in_sizes, int n_in,
                              void* d_out, int out_size, void* d_ws, size_t ws_size,
                              hipStream_t stream) {
  const float* x0 = (const float*)d_in[0];
  const int* ei = (const int*)d_in[1];

  const int N = in_sizes[0] / 4;       // 10000
  const int E = in_sizes[1] / 2;       // 160000
  const int ETOT = E + N;              // 170000
  const int MTILES = (N + 127) / 128;  // 79
  const int MPAD = MTILES * 128;       // 10112

  struct LayerP { const float *Wl, *bl, *Wr, *br, *att, *bias; int fi, fo; };
  LayerP L[3] = {
      {(const float*)d_in[2],  (const float*)d_in[3],  (const float*)d_in[4],
       (const float*)d_in[5],  (const float*)d_in[6],  (const float*)d_in[7],  4, 128},
      {(const float*)d_in[8],  (const float*)d_in[9],  (const float*)d_in[10],
       (const float*)d_in[11], (const float*)d_in[12], (const float*)d_in[13], 128, 512},
      {(const float*)d_in[14], (const float*)d_in[15], (const float*)d_in[16],
       (const float*)d_in[17], (const float*)d_in[18], (const float*)d_in[19], 512, 1028},
  };

  char* w = (char*)d_ws;
  auto alloc = [&](size_t bytes) { char* p = w; w += align16(bytes); return p; };
  int* counts   = (int*)alloc((size_t)N * 4);
  int* row_ptr  = (int*)alloc((size_t)(N + 1) * 4);
  int* cursor   = (int*)alloc((size_t)N * 4);
  int* col_src  = (int*)alloc((size_t)ETOT * 4);
  int* col_dst  = (int*)alloc((size_t)ETOT * 4);
  // xlh/xrh: N x 2056 floats each; used as two ping/pong slabs per layer
  float* xlh    = (float*)alloc((size_t)N * 2056 * 4);
  float* xrh    = (float*)alloc((size_t)N * 2056 * 4);
  float* h1     = (float*)alloc((size_t)N * 128 * 4);
  float* h2     = (float*)alloc((size_t)N * 512 * 4);
  float* acc12  = (float*)alloc((size_t)N * 512 * 4);
  bf16_t* xph   = (bf16_t*)alloc((size_t)MPAD * 512 * 2);
  bf16_t* xpl   = (bf16_t*)alloc((size_t)MPAD * 512 * 2);
  // layer-3 packed W: 2 ping/pong slots of (1 head x Npad=1152 x K=512)
  const size_t W3G = (size_t)1152 * 512;
  bf16_t* w3hL  = (bf16_t*)alloc(2 * W3G * 2);
  bf16_t* w3lL  = (bf16_t*)alloc(2 * W3G * 2);
  bf16_t* w3hR  = (bf16_t*)alloc(2 * W3G * 2);
  bf16_t* w3lR  = (bf16_t*)alloc(2 * W3G * 2);
  // layer-2 all-heads packed W (Npad=512, K=128)
  const size_t WPK2 = (size_t)HEADS * 512 * 128;
  bf16_t* w2hL  = (bf16_t*)alloc(WPK2 * 2);
  bf16_t* w2lL  = (bf16_t*)alloc(WPK2 * 2);
  bf16_t* w2hR  = (bf16_t*)alloc(WPK2 * 2);
  bf16_t* w2lR  = (bf16_t*)alloc(WPK2 * 2);

  // ---- CSR build (dst-sorted) ----
  init_counts_kernel<<<(N + 255) / 256, 256, 0, stream>>>(counts, N);
  count_kernel<<<(E + 255) / 256, 256, 0, stream>>>(ei + E, counts, E);
  scan_kernel<<<1, 1024, 0, stream>>>(counts, row_ptr, cursor, N);
  scatter_edges_kernel<<<(E + 255) / 256, 256, 0, stream>>>(ei, cursor, col_src, col_dst, E);
  scatter_loops_kernel<<<(N + 255) / 256, 256, 0, stream>>>(cursor, col_src, col_dst, N);

  // ---- layer 1 (fp32 GEMM, 8-head groups of C=1024; serial, small) ----
  {
    int C = 128;
    float* acc = acc12;
    for (int g = 0; g < 4; g++) {
      dim3 ggrid(8, MTILES, 2);
      gemm128<<<ggrid, 256, 0, stream>>>(x0, L[0].Wl, L[0].Wr, L[0].bl, L[0].br,
                                         xlh, xrh, N, 4, 1024, HEADS * C, g * 1024);
      edge_solo<1, 32><<<N, 256, 0, stream>>>(row_ptr, col_src, xlh, xrh,
                                              256, (size_t)32,
                                              L[0].att + (size_t)(g * 8) * C,
                                              acc, C, g * 8, 8);
    }
    finalize_kernel<<<((size_t)N * C + 255) / 256, 256, 0, stream>>>(acc, L[0].bias, h1,
                                                                     N * C, C, 1);
  }

  // ---- layer 2 (K=128, C=512; G=2, 16 groups; edge(g) || gemm(g+1)) ----
  {
    int fi = 128, C = 512, ldW = HEADS * C, Npadh = 512, G = 2;
    float* acc = acc12;
    size_t bufStride = (size_t)N * 1024;   // floats per ping/pong slab
    size_t hstr = (size_t)N * C;           // floats per head slab
    int total = MPAD * (fi >> 3);
    cvt_pack_kernel<<<(total + 255) / 256, 256, 0, stream>>>(h1, xph, xpl, N, MPAD, fi);
    int wtotal = HEADS * Npadh * (fi >> 3);
    dim3 wgrid((wtotal + 255) / 256, 2);
    pack_w_group_kernel<<<wgrid, 256, 0, stream>>>(L[1].Wl, L[1].Wr, w2hL, w2lL, w2hR, w2lR,
                                                   fi, C, Npadh, ldW, 0, HEADS);
    size_t whstride = (size_t)Npadh * fi;
    int gx = Npadh / 128, gy = MTILES, gz = 2 * G;
    int nwg = gx * gy * gz;
    const int NGR = HEADS / G;  // 16
    // prologue: gemm group 0 -> buf0
    fused_step<2, 64><<<nwg, 256, 0, stream>>>(
        row_ptr, col_src, xlh, xrh, C / 4, hstr / 4, L[1].att, acc, C, 0, G, 0,
        gx, gy, gz, xph, xpl, w2hL, w2lL, w2hR, w2lR, whstride,
        L[1].bl, L[1].br, xlh, xrh, hstr, N, fi, C, 0,
        0, L[1].Wl, L[1].Wr, w2hL, w2lL, w2hR, w2lR, fi, C, Npadh, ldW, 0, 0);
    for (int g = 0; g < NGR; g++) {
      int gn = g + 1;
      bool hasG = gn < NGR;
      int gni = hasG ? gn : 0;
      int tot = N + (hasG ? nwg : 0);
      fused_step<2, 64><<<tot, 256, 0, stream>>>(
          row_ptr, col_src,
          xlh + (size_t)(g & 1) * bufStride, xrh + (size_t)(g & 1) * bufStride,
          C / 4, hstr / 4, L[1].att + (size_t)(G * g) * C, acc, C, G * g, G, N,
          hasG ? gx : 0, gy, gz, xph, xpl,
          w2hL + (size_t)(G * gni) * whstride, w2lL + (size_t)(G * gni) * whstride,
          w2hR + (size_t)(G * gni) * whstride, w2lR + (size_t)(G * gni) * whstride,
          whstride, L[1].bl, L[1].br,
          xlh + (size_t)(gni & 1) * bufStride, xrh + (size_t)(gni & 1) * bufStride,
          hstr, N, fi, C, G * gni,
          0, L[1].Wl, L[1].Wr, w2hL, w2lL, w2hR, w2lR, fi, C, Npadh, ldW, 0, 0);
    }
    finalize_kernel<<<((size_t)N * C + 255) / 256, 256, 0, stream>>>(acc, L[1].bias, h2,
                                                                     N * C, C, 1);
  }

  // ---- layer 3 (K=512, C=1028; G=1, 32 groups; edge(g) || gemm(g+1) || pack(g+2)) ----
  {
    int fi = 512, C = 1028, ldW = HEADS * C, Npadh = 1152, G = 1;
    float* acc = (float*)d_out;
    size_t bufStride = (size_t)N * 1028;
    int total = MPAD * (fi >> 3);
    cvt_pack_kernel<<<(total + 255) / 256, 256, 0, stream>>>(h2, xph, xpl, N, MPAD, fi);
    int gx = Npadh / 128, gy = MTILES, gz = 2;  // G=1 -> gz=2 sides
    int nwg = gx * gy * gz;                     // 1422
    int pwtotal = Npadh * (fi >> 3);            // 73728 threads per side
    int pps = (pwtotal + 255) / 256;            // 288 blocks per side
    // prologue A: pack group 0 -> w3 slot 0
    dim3 wgrid(pps, 2);
    pack_w_group_kernel<<<wgrid, 256, 0, stream>>>(L[2].Wl, L[2].Wr,
                                                   w3hL, w3lL, w3hR, w3lR,
                                                   fi, C, Npadh, ldW, 0, 1);
    // prologue B: gemm group 0 (slot 0 -> buf0) || pack group 1 -> slot 1
    fused_step<5, 64><<<nwg + 2 * pps, 256, 0, stream>>>(
        row_ptr, col_src, xlh, xrh, C / 4, 0, L[2].att, acc, C, 0, G, 0,
        gx, gy, gz, xph, xpl, w3hL, w3lL, w3hR, w3lR, W3G,
        L[2].bl, L[2].br, xlh, xrh, bufStride, N, fi, C, 0,
        pps, L[2].Wl, L[2].Wr, w3hL + W3G, w3lL + W3G, w3hR + W3G, w3lR + W3G,
        fi, C, Npadh, ldW, 1, 1);
    for (int g = 0; g < HEADS; g++) {
      int gn = g + 1, gp = g + 2;
      bool hasG = gn < HEADS, hasP = gp < HEADS;
      int gni = hasG ? gn : 0, gpi = hasP ? gp : 0;
      int tot = N + (hasG ? nwg : 0) + (hasP ? 2 * pps : 0);
      fused_step<5, 64><<<tot, 256, 0, stream>>>(
          row_ptr, col_src,
          xlh + (size_t)(g & 1) * bufStride, xrh + (size_t)(g & 1) * bufStride,
          C / 4, 0, L[2].att + (size_t)g * C, acc, C, g, 1, N,
          hasG ? gx : 0, gy, gz, xph, xpl,
          w3hL + (size_t)(gni & 1) * W3G, w3lL + (size_t)(gni & 1) * W3G,
          w3hR + (size_t)(gni & 1) * W3G, w3lR + (size_t)(gni & 1) * W3G,
          W3G, L[2].bl, L[2].br,
          xlh + (size_t)(gni & 1) * bufStride, xrh + (size_t)(gni & 1) * bufStride,
          bufStride, N, fi, C, gni,
          hasP ? pps : 0, L[2].Wl, L[2].Wr,
          w3hL + (size_t)(gpi & 1) * W3G, w3lL + (size_t)(gpi & 1) * W3G,
          w3hR + (size_t)(gpi & 1) * W3G, w3lR + (size_t)(gpi & 1) * W3G,
          fi, C, Npadh, ldW, gpi, 1);
    }
    finalize_kernel<<<((size_t)N * C + 255) / 256, 256, 0, stream>>>(acc, L[2].bias, (float*)d_out,
                                                                     N * C, C, 0);
  }
}

// Round 6
// 8771.439 us; speedup vs baseline: 1.3201x; 1.3201x over previous
//
#include <hip/hip_runtime.h>
#include <hip/hip_fp16.h>
#include <cstddef>
#include <cstdint>

// ---------------------------------------------------------------------------
// GATv2 x3 layers. R11 (fp16 gather stream):
//  - R10 post-mortem: single-kernel role fusion forces worst-case VGPR/LDS on
//    edge blocks -> occupancy 21%, BW 2.3 TB/s. Reverted to R8 structure.
//  - xl slabs for layers 2/3 stored as fp16 (GEMM epilogue converts; C=1028
//    padded to ldh=1032 with zeros). Edge kernel gathers half8 per lane:
//    halves the dominant E*G*C*4 gather traffic AND the request count.
//    xr/att/accum stay fp32 (only xl quantization error enters output).
//  - edge_fused_half<HPT>: HPT=1 (C=512, no stash) / HPT=3 (C=1028, stash
//    converted floats in slab LDS, register row-buffer stays small).
//  - R8 kept: __expf, 2-op leaky, WIDTH=32 fp32 edge for layer 1.
//  - R7 kept: XCD-chunked GEMM swizzle, global_load_lds, split-bf16 3-MFMA.
// ---------------------------------------------------------------------------

#define HEADS 32
#define SLOPE_ATT 0.2f
#define SLOPE_ACT 0.01f

typedef __bf16 bf16_t;
typedef __bf16 bf16x8 __attribute__((ext_vector_type(8)));
typedef float f32x16 __attribute__((ext_vector_type(16)));

#define GLDS16(gp, lp)                                                        \
  __builtin_amdgcn_global_load_lds(                                           \
      (const __attribute__((address_space(1))) void*)(gp),                    \
      (__attribute__((address_space(3))) void*)(lp), 16, 0, 0)

// ---------------- CSR build ----------------

__global__ __launch_bounds__(256) void init_counts_kernel(int* counts, int n) {
  int i = blockIdx.x * 256 + threadIdx.x;
  if (i < n) counts[i] = 1;  // self-loop
}

__global__ __launch_bounds__(256) void count_kernel(const int* __restrict__ dst, int* counts, int E) {
  int e = blockIdx.x * 256 + threadIdx.x;
  if (e < E) atomicAdd(&counts[dst[e]], 1);
}

__global__ __launch_bounds__(1024) void scan_kernel(const int* __restrict__ counts,
                                                    int* __restrict__ row_ptr,
                                                    int* __restrict__ cursor, int n) {
  __shared__ int sums[1024];
  int t = threadIdx.x;
  int per = (n + 1023) >> 10;
  int base = t * per;
  int s = 0;
  for (int i = 0; i < per; i++) { int idx = base + i; if (idx < n) s += counts[idx]; }
  sums[t] = s;
  __syncthreads();
  for (int off = 1; off < 1024; off <<= 1) {
    int v = (t >= off) ? sums[t - off] : 0;
    __syncthreads();
    sums[t] += v;
    __syncthreads();
  }
  int run = (t == 0) ? 0 : sums[t - 1];
  for (int i = 0; i < per; i++) {
    int idx = base + i;
    if (idx < n) { row_ptr[idx] = run; cursor[idx] = run; run += counts[idx]; }
  }
  if (t == 1023) row_ptr[n] = sums[1023];
}

__global__ __launch_bounds__(256) void scatter_edges_kernel(const int* __restrict__ ei, int* cursor,
                                                            int* col_src, int* col_dst, int E) {
  int e = blockIdx.x * 256 + threadIdx.x;
  if (e >= E) return;
  int src = ei[e], dst = ei[E + e];
  int pos = atomicAdd(&cursor[dst], 1);
  col_src[pos] = src;
  col_dst[pos] = dst;
}

__global__ __launch_bounds__(256) void scatter_loops_kernel(int* cursor, int* col_src, int* col_dst, int N) {
  int nid = blockIdx.x * 256 + threadIdx.x;
  if (nid >= N) return;
  int pos = atomicAdd(&cursor[nid], 1);
  col_src[pos] = nid;
  col_dst[pos] = nid;
}

// ---------------- split-bf16 pack: X[M,K] fp32 -> frag-major hi/lo ----------------

__global__ __launch_bounds__(256) void cvt_pack_kernel(const float* __restrict__ X,
                                                       bf16_t* __restrict__ hi,
                                                       bf16_t* __restrict__ lo,
                                                       int M, int Mpad, int K) {
  int t = blockIdx.x * 256 + threadIdx.x;
  int kchunks = K >> 3;
  int total = Mpad * kchunks;
  if (t >= total) return;
  int kc = t % kchunks;
  int m = t / kchunks;
  int mt = m >> 7, ml = m & 127;
  size_t o = ((size_t)(mt * kchunks + kc)) * 1024 + (size_t)ml * 8;
  float v[8];
  if (m < M) {
    float4 a = *(const float4*)(X + (size_t)m * K + kc * 8);
    float4 b = *(const float4*)(X + (size_t)m * K + kc * 8 + 4);
    v[0] = a.x; v[1] = a.y; v[2] = a.z; v[3] = a.w;
    v[4] = b.x; v[5] = b.y; v[6] = b.z; v[7] = b.w;
  } else {
#pragma unroll
    for (int i = 0; i < 8; i++) v[i] = 0.f;
  }
  union { bf16_t h[8]; float4 f; } uh, ul;
#pragma unroll
  for (int i = 0; i < 8; i++) {
    bf16_t h = (bf16_t)v[i];
    uh.h[i] = h;
    ul.h[i] = (bf16_t)(v[i] - (float)h);
  }
  *(float4*)(hi + o) = uh.f;
  *(float4*)(lo + o) = ul.f;
}

// ---------------- W pack, G heads starting at h0 ----------------

__global__ __launch_bounds__(256) void pack_w_group_kernel(const float* __restrict__ Wl,
                                                           const float* __restrict__ Wr,
                                                           bf16_t* __restrict__ hL, bf16_t* __restrict__ lL,
                                                           bf16_t* __restrict__ hR, bf16_t* __restrict__ lR,
                                                           int K, int C, int Npad, int ldW,
                                                           int h0, int G) {
  int side = blockIdx.y;
  const float* W = side ? Wr : Wl;
  bf16_t* Hi = side ? hR : hL;
  bf16_t* Lo = side ? lR : lL;
  int kchunks = K >> 3;
  int perhead = Npad * kchunks;
  int t = blockIdx.x * 256 + threadIdx.x;
  if (t >= G * perhead) return;
  int g = t / perhead, rem = t % perhead;
  int n = rem % Npad, kc = rem / Npad;
  int nt = n >> 7, nl = n & 127;
  size_t o = (size_t)g * Npad * K + ((size_t)(nt * kchunks + kc)) * 1024 + (size_t)nl * 8;
  int col0 = (h0 + g) * C;
  union { bf16_t hh[8]; float4 f; } uh, ul;
#pragma unroll
  for (int kk = 0; kk < 8; kk++) {
    int k = kc * 8 + kk;
    float v = (n < C) ? W[(size_t)k * ldW + col0 + n] : 0.f;
    bf16_t hv = (bf16_t)v;
    uh.hh[kk] = hv;
    ul.hh[kk] = (bf16_t)(v - (float)hv);
  }
  *(float4*)(Hi + o) = uh.f;
  *(float4*)(Lo + o) = ul.f;
}

// ---------------- MFMA GEMM 128x128, 256 thr, head-batched z, DMA staging ----
// side 0 (L) writes __half with ldh-padded rows (pad cols zeroed);
// side 1 (R) writes fp32. XCD-chunked swizzle (bijective, m204) + NY=8
// y-rectangle order for L2 reuse.

__global__ __launch_bounds__(256) void gemm_mfma_v6(const bf16_t* __restrict__ Xh,
                                                    const bf16_t* __restrict__ Xl,
                                                    const bf16_t* __restrict__ BhL,
                                                    const bf16_t* __restrict__ BlL,
                                                    const bf16_t* __restrict__ BhR,
                                                    const bf16_t* __restrict__ BlR,
                                                    size_t bHeadStride,
                                                    const float* __restrict__ bl,
                                                    const float* __restrict__ br,
                                                    __half* __restrict__ outLh,
                                                    size_t outLStrideH, int ldh,
                                                    float* __restrict__ outR,
                                                    size_t outRStride,
                                                    int M, int K, int C, int h0) {
  // ---- block swizzle ----
  int gx = gridDim.x, gy = gridDim.y, gz = gridDim.z;
  int nwg = gx * gy * gz;
  int p = blockIdx.x + gx * (blockIdx.y + gy * blockIdx.z);
  int q = nwg >> 3, r = nwg & 7;
  int xcd = p & 7, slot = p >> 3;
  int lid = (xcd < r ? xcd * (q + 1) : r * (q + 1) + (xcd - r) * q) + slot;
  const int NY = 8;
  int xzsz = gx * gz;
  int fullr = gy / NY;
  int lidf = fullr * NY * xzsz;
  int rectbase, ny, rem;
  if (lid < lidf) {
    int rect = lid / (NY * xzsz);
    rem = lid - rect * (NY * xzsz);
    rectbase = rect * NY;
    ny = NY;
  } else {
    rem = lid - lidf;
    rectbase = fullr * NY;
    ny = gy - rectbase;
  }
  int xz = rem / ny;
  int yl = rem - xz * ny;
  int bx = xz % gx;
  int bz = xz / gx;
  int by = rectbase + yl;

  int g = bz >> 1, side = bz & 1;
  const bf16_t* Bh = (side ? BhR : BhL) + (size_t)g * bHeadStride;
  const bf16_t* Bl = (side ? BlR : BlL) + (size_t)g * bHeadStride;
  const float* bias = side ? br : bl;
  int col0 = (h0 + g) * C;

  __shared__ __align__(16) bf16_t AsH[4 * 128 * 8];   // 8KB each
  __shared__ __align__(16) bf16_t AsL[4 * 128 * 8];
  __shared__ __align__(16) bf16_t BsH[4 * 128 * 8];
  __shared__ __align__(16) bf16_t BsL[4 * 128 * 8];

  int tid = threadIdx.x;
  int wave = tid >> 6, lane = tid & 63;
  int l31 = lane & 31, lhalf = lane >> 5;
  int mt = by;
  int ntb = bx * 128;
  int m0 = mt * 128;
  int kchunks = K >> 3;

  const bf16_t* Ah = Xh + (size_t)mt * K * 128;
  const bf16_t* Al = Xl + (size_t)mt * K * 128;
  const bf16_t* Bhp = Bh + (size_t)bx * kchunks * 1024;
  const bf16_t* Blp = Bl + (size_t)bx * kchunks * 1024;

  auto* asH3 = (__attribute__((address_space(3))) bf16_t*)AsH;
  auto* asL3 = (__attribute__((address_space(3))) bf16_t*)AsL;
  auto* bsH3 = (__attribute__((address_space(3))) bf16_t*)BsH;
  auto* bsL3 = (__attribute__((address_space(3))) bf16_t*)BsL;

  f32x16 acc[4];
#pragma unroll
  for (int i = 0; i < 4; i++)
#pragma unroll
    for (int rr = 0; rr < 16; rr++) acc[i][rr] = 0.f;

  for (int k0 = 0; k0 < K; k0 += 32) {
    int kc0 = k0 >> 3;
#pragma unroll
    for (int rr = 0; rr < 2; rr++) {
      int idx = tid + 256 * rr;
      size_t off = ((size_t)(kc0 + (idx >> 7))) * 1024 + (size_t)(idx & 127) * 8;
      int li = idx * 8;
      GLDS16(Ah + off, asH3 + li);
      GLDS16(Al + off, asL3 + li);
      GLDS16(Bhp + off, bsH3 + li);
      GLDS16(Blp + off, bsL3 + li);
    }
    __syncthreads();

#pragma unroll
    for (int s = 0; s < 2; s++) {
      int c = s * 2 + lhalf;
      int abase = (c * 128 + wave * 32 + l31) * 8;
      bf16x8 ah = *(const bf16x8*)&AsH[abase];
      bf16x8 al = *(const bf16x8*)&AsL[abase];
#pragma unroll
      for (int nt = 0; nt < 4; nt++) {
        int bbase = (c * 128 + nt * 32 + l31) * 8;
        bf16x8 bh = *(const bf16x8*)&BsH[bbase];
        bf16x8 blo = *(const bf16x8*)&BsL[bbase];
        acc[nt] = __builtin_amdgcn_mfma_f32_32x32x16_bf16(ah, bh, acc[nt], 0, 0, 0);
        acc[nt] = __builtin_amdgcn_mfma_f32_32x32x16_bf16(ah, blo, acc[nt], 0, 0, 0);
        acc[nt] = __builtin_amdgcn_mfma_f32_32x32x16_bf16(al, bh, acc[nt], 0, 0, 0);
      }
    }
    __syncthreads();
  }

  // epilogue: C/D layout col=lane&31, row=(r&3)+8*(r>>2)+4*(lane>>5)
  if (side == 0) {
    __half* out = outLh + (size_t)g * outLStrideH;
#pragma unroll
    for (int nt = 0; nt < 4; nt++) {
      int n = ntb + nt * 32 + l31;
      if (n >= ldh) continue;
      float bv = (n < C) ? bias[col0 + n] : 0.f;
#pragma unroll
      for (int rr = 0; rr < 16; rr++) {
        int row = (rr & 3) + 8 * (rr >> 2) + 4 * lhalf;
        int m = m0 + wave * 32 + row;
        if (m < M) {
          float val = (n < C) ? (acc[nt][rr] + bv) : 0.f;
          out[(size_t)m * ldh + n] = __float2half(val);
        }
      }
    }
  } else {
    float* out = outR + (size_t)g * outRStride;
#pragma unroll
    for (int nt = 0; nt < 4; nt++) {
      int n = ntb + nt * 32 + l31;
      if (n >= C) continue;
      float bv = bias[col0 + n];
#pragma unroll
      for (int rr = 0; rr < 16; rr++) {
        int row = (rr & 3) + 8 * (rr >> 2) + 4 * lhalf;
        int m = m0 + wave * 32 + row;
        if (m < M) out[(size_t)m * C + n] = acc[nt][rr] + bv;
      }
    }
  }
}

// ---------------- fp32 GEMM (layer 1, K=4), grouped heads ----------------

#define BM 128
#define BN 128
#define BK 16
#define LDA (BM + 4)
#define LDB (BN + 4)

__global__ __launch_bounds__(256) void gemm128(const float* __restrict__ X,
                                               const float* __restrict__ Wl,
                                               const float* __restrict__ Wr,
                                               const float* __restrict__ bl,
                                               const float* __restrict__ br,
                                               float* __restrict__ outL,
                                               float* __restrict__ outR,
                                               int M, int K, int C, int ldW, int col0) {
  const float* W = blockIdx.z ? Wr : Wl;
  const float* bias = blockIdx.z ? br : bl;
  float* out = blockIdx.z ? outR : outL;

  __shared__ __align__(16) float As[BK][LDA];
  __shared__ __align__(16) float Bs[BK][LDB];

  int t = threadIdx.x;
  int tx = t & 15, ty = t >> 4;
  int m0 = blockIdx.y * BM, n0 = blockIdx.x * BN;

  float acc00[4][4] = {}, acc01[4][4] = {}, acc10[4][4] = {}, acc11[4][4] = {};

  for (int k0 = 0; k0 < K; k0 += BK) {
    {
      int kk = (t & 3) * 4;
#pragma unroll
      for (int p = 0; p < 2; p++) {
        int row = (t >> 2) + p * 64;
        int m = m0 + row;
        float4 v = make_float4(0.f, 0.f, 0.f, 0.f);
        if (m < M && (k0 + kk) < K)
          v = *(const float4*)(X + (size_t)m * K + k0 + kk);
        As[kk + 0][row] = v.x; As[kk + 1][row] = v.y;
        As[kk + 2][row] = v.z; As[kk + 3][row] = v.w;
      }
    }
    {
      int kk = t >> 4;
#pragma unroll
      for (int qq = 0; qq < 2; qq++) {
        int cn = (t & 15) * 4 + qq * 64;
        int n = n0 + cn;
        float4 v = make_float4(0.f, 0.f, 0.f, 0.f);
        if ((k0 + kk) < K && n + 3 < C)
          v = *(const float4*)(W + (size_t)(k0 + kk) * ldW + col0 + n);
        *(float4*)&Bs[kk][cn] = v;
      }
    }
    __syncthreads();

    int kmax = min(BK, K - k0);
    for (int kk = 0; kk < kmax; kk++) {
      float4 a0 = *(const float4*)&As[kk][ty * 4];
      float4 a1 = *(const float4*)&As[kk][64 + ty * 4];
      float4 b0 = *(const float4*)&Bs[kk][tx * 4];
      float4 b1 = *(const float4*)&Bs[kk][64 + tx * 4];
      float af0[4] = {a0.x, a0.y, a0.z, a0.w};
      float af1[4] = {a1.x, a1.y, a1.z, a1.w};
      float bf0[4] = {b0.x, b0.y, b0.z, b0.w};
      float bf1[4] = {b1.x, b1.y, b1.z, b1.w};
#pragma unroll
      for (int i = 0; i < 4; i++)
#pragma unroll
        for (int j = 0; j < 4; j++) {
          acc00[i][j] += af0[i] * bf0[j];
          acc01[i][j] += af0[i] * bf1[j];
          acc10[i][j] += af1[i] * bf0[j];
          acc11[i][j] += af1[i] * bf1[j];
        }
    }
    __syncthreads();
  }

#pragma unroll
  for (int ma = 0; ma < 2; ma++) {
#pragma unroll
    for (int i = 0; i < 4; i++) {
      int m = m0 + ma * 64 + ty * 4 + i;
      if (m >= M) continue;
#pragma unroll
      for (int nb = 0; nb < 2; nb++) {
        int n = n0 + nb * 64 + tx * 4;
        float (*blk)[4] = (ma == 0) ? ((nb == 0) ? acc00 : acc01)
                                    : ((nb == 0) ? acc10 : acc11);
        if (n + 3 < C) {
          float4 bv = *(const float4*)(bias + col0 + n);
          float4 o = make_float4(blk[i][0] + bv.x, blk[i][1] + bv.y,
                                 blk[i][2] + bv.z, blk[i][3] + bv.w);
          *(float4*)(out + (size_t)m * C + n) = o;
        }
      }
    }
  }
}

// ---------------- fp32 multi-head edge kernel (layer 1, online softmax) -----

template <int F4PT, int WIDTH>
__global__ __launch_bounds__(256) void edge_fused_multi(const int* __restrict__ row_ptr,
                                                        const int* __restrict__ col_src,
                                                        const float* __restrict__ xl,
                                                        const float* __restrict__ xr,
                                                        int ld4, size_t hstride4,
                                                        const float* __restrict__ att,
                                                        float* __restrict__ acc,
                                                        int C, int head0, int G) {
  constexpr int NG = 256 / WIDTH;
  constexpr int ROW = F4PT * WIDTH;
  constexpr int ITER = (ROW + 255) / 256;
  int node = blockIdx.x;
  int tid = threadIdx.x;
  int grp = tid / WIDTH, lane = tid % WIDTH;
  int C4 = C >> 2;
  int s = row_ptr[node], t = row_ptr[node + 1];

  __shared__ __align__(16) float4 slab[NG][ROW];
  __shared__ float mred[NG], dred[NG];

  float4 vtot[ITER];
#pragma unroll
  for (int it = 0; it < ITER; it++) vtot[it] = make_float4(0.f, 0.f, 0.f, 0.f);

  for (int g = 0; g < G; g++) {
    const float4* xlb = (const float4*)xl + (size_t)g * hstride4;
    const float4* xrp = (const float4*)xr + (size_t)g * hstride4 + (size_t)node * ld4;
    const float4* ap = (const float4*)(att + (size_t)g * C);

    float4 xr4[F4PT], a4[F4PT], o4[F4PT];
#pragma unroll
    for (int k = 0; k < F4PT; k++) {
      int c4 = k * WIDTH + lane;
      bool ok = (c4 < C4);
      xr4[k] = ok ? xrp[c4] : make_float4(0.f, 0.f, 0.f, 0.f);
      a4[k] = ok ? ap[c4] : make_float4(0.f, 0.f, 0.f, 0.f);
      o4[k] = make_float4(0.f, 0.f, 0.f, 0.f);
    }
    float m = -1e30f, den = 0.f;

    for (int j = s + grp; j < t; j += NG) {
      int src = col_src[j];
      const float4* xlp = xlb + (size_t)src * ld4;
      float4 x4[F4PT];
      float e = 0.f;
#pragma unroll
      for (int k = 0; k < F4PT; k++) {
        int c4 = k * WIDTH + lane;
        x4[k] = (c4 < C4) ? xlp[c4] : make_float4(0.f, 0.f, 0.f, 0.f);
        float v;
        v = x4[k].x + xr4[k].x; v = fmaxf(v, SLOPE_ATT * v); e = fmaf(a4[k].x, v, e);
        v = x4[k].y + xr4[k].y; v = fmaxf(v, SLOPE_ATT * v); e = fmaf(a4[k].y, v, e);
        v = x4[k].z + xr4[k].z; v = fmaxf(v, SLOPE_ATT * v); e = fmaf(a4[k].z, v, e);
        v = x4[k].w + xr4[k].w; v = fmaxf(v, SLOPE_ATT * v); e = fmaf(a4[k].w, v, e);
      }
#pragma unroll
      for (int off = 1; off < WIDTH; off <<= 1) e += __shfl_xor(e, off, 64);

      if (e <= m) {  // group-uniform branch
        float p = __expf(e - m);
        den += p;
#pragma unroll
        for (int k = 0; k < F4PT; k++) {
          o4[k].x = fmaf(p, x4[k].x, o4[k].x); o4[k].y = fmaf(p, x4[k].y, o4[k].y);
          o4[k].z = fmaf(p, x4[k].z, o4[k].z); o4[k].w = fmaf(p, x4[k].w, o4[k].w);
        }
      } else {
        float sc = __expf(m - e);  // m=-1e30 first time -> 0
        den = fmaf(den, sc, 1.f);
#pragma unroll
        for (int k = 0; k < F4PT; k++) {
          o4[k].x = fmaf(o4[k].x, sc, x4[k].x); o4[k].y = fmaf(o4[k].y, sc, x4[k].y);
          o4[k].z = fmaf(o4[k].z, sc, x4[k].z); o4[k].w = fmaf(o4[k].w, sc, x4[k].w);
        }
        m = e;
      }
    }

    if (lane == 0) { mred[grp] = m; dred[grp] = den; }
    __syncthreads();
    float M2 = -1e30f;
#pragma unroll
    for (int i = 0; i < NG; i++) M2 = fmaxf(M2, mred[i]);
    float dtot = 0.f;
#pragma unroll
    for (int i = 0; i < NG; i++) dtot += dred[i] * __expf(mred[i] - M2);
    float f = __expf(m - M2);
#pragma unroll
    for (int k = 0; k < F4PT; k++) {
      float4 w4 = make_float4(o4[k].x * f, o4[k].y * f, o4[k].z * f, o4[k].w * f);
      slab[grp][k * WIDTH + lane] = w4;
    }
    __syncthreads();
    float inv = 1.0f / dtot;
#pragma unroll
    for (int it = 0; it < ITER; it++) {
      int c4 = tid + it * 256;
      if (c4 < ROW && c4 < C4) {
        float sx = 0.f, sy = 0.f, sz = 0.f, sw = 0.f;
#pragma unroll
        for (int i = 0; i < NG; i++) {
          float4 sv = slab[i][c4];
          sx += sv.x; sy += sv.y; sz += sv.z; sw += sv.w;
        }
        vtot[it].x = fmaf(sx, inv, vtot[it].x);
        vtot[it].y = fmaf(sy, inv, vtot[it].y);
        vtot[it].z = fmaf(sz, inv, vtot[it].z);
        vtot[it].w = fmaf(sw, inv, vtot[it].w);
      }
    }
    __syncthreads();  // slab reused next head
  }

  float4* accp = (float4*)(acc + (size_t)node * C);
#pragma unroll
  for (int it = 0; it < ITER; it++) {
    int c4 = tid + it * 256;
    if (c4 < ROW && c4 < C4) {
      if (head0 == 0) {
        accp[c4] = vtot[it];
      } else {
        float4 prev = accp[c4];
        accp[c4] = make_float4(prev.x + vtot[it].x, prev.y + vtot[it].y,
                               prev.z + vtot[it].z, prev.w + vtot[it].w);
      }
    }
  }
}

// ---------------- fp16-gather edge kernel (layers 2/3) ----------------------
// xl slab is __half with row stride ldh (multiple of 8, zero-padded past C).
// Each lane loads HPT half8 units (uint4) per edge; xr/att/accum fp32.
// HPT>=2: converted row parked in slab LDS (stash) to cap registers.

template <int HPT>
__global__ __launch_bounds__(256) void edge_fused_half(const int* __restrict__ row_ptr,
                                                       const int* __restrict__ col_src,
                                                       const __half* __restrict__ xl,
                                                       const float* __restrict__ xr,
                                                       int ldh, size_t hstrH,
                                                       int ldr4, size_t hstrR4,
                                                       const float* __restrict__ att,
                                                       float* __restrict__ acc,
                                                       int C, int head0, int G) {
  constexpr int NG = 4;
  constexpr int ROW = 2 * HPT * 64;  // float4 slots per group
  constexpr int ITER = (ROW + 255) / 256;
  constexpr bool STASH = (HPT >= 2);
  int node = blockIdx.x;
  int tid = threadIdx.x;
  int grp = tid >> 6, lane = tid & 63;
  int C4 = C >> 2;
  int units = ldh >> 3;
  int s = row_ptr[node], t = row_ptr[node + 1];

  __shared__ __align__(16) float4 slab[NG][ROW];
  __shared__ float mred[NG], dred[NG];

  float4 vtot[ITER];
#pragma unroll
  for (int it = 0; it < ITER; it++) vtot[it] = make_float4(0.f, 0.f, 0.f, 0.f);

  for (int g = 0; g < G; g++) {
    const __half* xlb = xl + (size_t)g * hstrH;
    const float4* xrp = (const float4*)xr + (size_t)g * hstrR4 + (size_t)node * ldr4;
    const float4* ap = (const float4*)(att + (size_t)g * C);

    float4 xr4[2 * HPT], a4[2 * HPT], o4[2 * HPT];
#pragma unroll
    for (int u = 0; u < HPT; u++) {
      int unit = u * 64 + lane;
#pragma unroll
      for (int h = 0; h < 2; h++) {
        int c4 = unit * 2 + h;
        bool ok = (c4 < C4);
        xr4[2 * u + h] = ok ? xrp[c4] : make_float4(0.f, 0.f, 0.f, 0.f);
        a4[2 * u + h] = ok ? ap[c4] : make_float4(0.f, 0.f, 0.f, 0.f);
        o4[2 * u + h] = make_float4(0.f, 0.f, 0.f, 0.f);
      }
    }
    float m = -1e30f, den = 0.f;

    for (int j = s + grp; j < t; j += NG) {
      int src = col_src[j];
      const __half* xrow = xlb + (size_t)src * ldh;
      float4 x4[2 * HPT];
      float e = 0.f;
#pragma unroll
      for (int u = 0; u < HPT; u++) {
        int unit = u * 64 + lane;
        uint4 raw = make_uint4(0u, 0u, 0u, 0u);
        if (unit < units) raw = *(const uint4*)(xrow + (size_t)unit * 8);
        union { uint4 q; __half2 h2[4]; } cv; cv.q = raw;
        float2 p0 = __half22float2(cv.h2[0]);
        float2 p1 = __half22float2(cv.h2[1]);
        float2 p2 = __half22float2(cv.h2[2]);
        float2 p3 = __half22float2(cv.h2[3]);
        float4 f0 = make_float4(p0.x, p0.y, p1.x, p1.y);
        float4 f1 = make_float4(p2.x, p2.y, p3.x, p3.y);
        if constexpr (STASH) {
          slab[grp][unit * 2 + 0] = f0;
          slab[grp][unit * 2 + 1] = f1;
        } else {
          x4[2 * u] = f0; x4[2 * u + 1] = f1;
        }
        float v;
        v = f0.x + xr4[2 * u].x; v = fmaxf(v, SLOPE_ATT * v); e = fmaf(a4[2 * u].x, v, e);
        v = f0.y + xr4[2 * u].y; v = fmaxf(v, SLOPE_ATT * v); e = fmaf(a4[2 * u].y, v, e);
        v = f0.z + xr4[2 * u].z; v = fmaxf(v, SLOPE_ATT * v); e = fmaf(a4[2 * u].z, v, e);
        v = f0.w + xr4[2 * u].w; v = fmaxf(v, SLOPE_ATT * v); e = fmaf(a4[2 * u].w, v, e);
        v = f1.x + xr4[2 * u + 1].x; v = fmaxf(v, SLOPE_ATT * v); e = fmaf(a4[2 * u + 1].x, v, e);
        v = f1.y + xr4[2 * u + 1].y; v = fmaxf(v, SLOPE_ATT * v); e = fmaf(a4[2 * u + 1].y, v, e);
        v = f1.z + xr4[2 * u + 1].z; v = fmaxf(v, SLOPE_ATT * v); e = fmaf(a4[2 * u + 1].z, v, e);
        v = f1.w + xr4[2 * u + 1].w; v = fmaxf(v, SLOPE_ATT * v); e = fmaf(a4[2 * u + 1].w, v, e);
      }
#pragma unroll
      for (int off = 1; off < 64; off <<= 1) e += __shfl_xor(e, off, 64);

      if (e <= m) {  // group-uniform branch
        float p = __expf(e - m);
        den += p;
#pragma unroll
        for (int u = 0; u < HPT; u++) {
          int unit = u * 64 + lane;
#pragma unroll
          for (int h = 0; h < 2; h++) {
            float4 xv;
            if constexpr (STASH) xv = slab[grp][unit * 2 + h];
            else xv = x4[2 * u + h];
            int k = 2 * u + h;
            o4[k].x = fmaf(p, xv.x, o4[k].x); o4[k].y = fmaf(p, xv.y, o4[k].y);
            o4[k].z = fmaf(p, xv.z, o4[k].z); o4[k].w = fmaf(p, xv.w, o4[k].w);
          }
        }
      } else {
        float sc = __expf(m - e);  // m=-1e30 first time -> 0
        den = fmaf(den, sc, 1.f);
#pragma unroll
        for (int u = 0; u < HPT; u++) {
          int unit = u * 64 + lane;
#pragma unroll
          for (int h = 0; h < 2; h++) {
            float4 xv;
            if constexpr (STASH) xv = slab[grp][unit * 2 + h];
            else xv = x4[2 * u + h];
            int k = 2 * u + h;
            o4[k].x = fmaf(o4[k].x, sc, xv.x); o4[k].y = fmaf(o4[k].y, sc, xv.y);
            o4[k].z = fmaf(o4[k].z, sc, xv.z); o4[k].w = fmaf(o4[k].w, sc, xv.w);
          }
        }
        m = e;
      }
    }

    if (lane == 0) { mred[grp] = m; dred[grp] = den; }
    __syncthreads();
    float M2 = -1e30f;
#pragma unroll
    for (int i = 0; i < NG; i++) M2 = fmaxf(M2, mred[i]);
    float dtot = 0.f;
#pragma unroll
    for (int i = 0; i < NG; i++) dtot += dred[i] * __expf(mred[i] - M2);
    float f = __expf(m - M2);
#pragma unroll
    for (int u = 0; u < HPT; u++) {
      int unit = u * 64 + lane;
#pragma unroll
      for (int h = 0; h < 2; h++) {
        int k = 2 * u + h;
        slab[grp][unit * 2 + h] =
            make_float4(o4[k].x * f, o4[k].y * f, o4[k].z * f, o4[k].w * f);
      }
    }
    __syncthreads();
    float inv = 1.0f / dtot;
#pragma unroll
    for (int it = 0; it < ITER; it++) {
      int c4 = tid + it * 256;
      if (c4 < ROW && c4 < C4) {
        float sx = 0.f, sy = 0.f, sz = 0.f, sw = 0.f;
#pragma unroll
        for (int i = 0; i < NG; i++) {
          float4 sv = slab[i][c4];
          sx += sv.x; sy += sv.y; sz += sv.z; sw += sv.w;
        }
        vtot[it].x = fmaf(sx, inv, vtot[it].x);
        vtot[it].y = fmaf(sy, inv, vtot[it].y);
        vtot[it].z = fmaf(sz, inv, vtot[it].z);
        vtot[it].w = fmaf(sw, inv, vtot[it].w);
      }
    }
    __syncthreads();  // slab reused next head
  }

  float4* accp = (float4*)(acc + (size_t)node * C);
#pragma unroll
  for (int it = 0; it < ITER; it++) {
    int c4 = tid + it * 256;
    if (c4 < ROW && c4 < C4) {
      if (head0 == 0) {
        accp[c4] = vtot[it];
      } else {
        float4 prev = accp[c4];
        accp[c4] = make_float4(prev.x + vtot[it].x, prev.y + vtot[it].y,
                               prev.z + vtot[it].z, prev.w + vtot[it].w);
      }
    }
  }
}

// ---------------- finalize: mean over heads + bias (+ leaky relu) ----------------

__global__ __launch_bounds__(256) void finalize_kernel(const float* __restrict__ acc,
                                                       const float* __restrict__ bias,
                                                       float* __restrict__ out,
                                                       int total, int C, int apply_act) {
  int i = blockIdx.x * 256 + threadIdx.x;
  if (i >= total) return;
  int c = i % C;
  float v = acc[i] * (1.0f / 32.0f) + bias[c];
  if (apply_act) v = fmaxf(v, SLOPE_ACT * v);
  out[i] = v;
}

// ---------------- host ----------------

static inline size_t align16(size_t x) { return (x + 15) & ~size_t(15); }

extern "C" void kernel_launch(void* const* d_in, const int* in_sizes, int n_in,
                              void* d_out, int out_size, void* d_ws, size_t ws_size,
                              hipStream_t stream) {
  const float* x0 = (const float*)d_in[0];
  const int* ei = (const int*)d_in[1];

  const int N = in_sizes[0] / 4;       // 10000
  const int E = in_sizes[1] / 2;       // 160000
  const int ETOT = E + N;              // 170000
  const int MTILES = (N + 127) / 128;  // 79
  const int MPAD = MTILES * 128;       // 10112

  struct LayerP { const float *Wl, *bl, *Wr, *br, *att, *bias; int fi, fo; };
  LayerP L[3] = {
      {(const float*)d_in[2],  (const float*)d_in[3],  (const float*)d_in[4],
       (const float*)d_in[5],  (const float*)d_in[6],  (const float*)d_in[7],  4, 128},
      {(const float*)d_in[8],  (const float*)d_in[9],  (const float*)d_in[10],
       (const float*)d_in[11], (const float*)d_in[12], (const float*)d_in[13], 128, 512},
      {(const float*)d_in[14], (const float*)d_in[15], (const float*)d_in[16],
       (const float*)d_in[17], (const float*)d_in[18], (const float*)d_in[19], 512, 1028},
  };

  char* w = (char*)d_ws;
  auto alloc = [&](size_t bytes) { char* p = w; w += align16(bytes); return p; };
  int* counts   = (int*)alloc((size_t)N * 4);
  int* row_ptr  = (int*)alloc((size_t)(N + 1) * 4);
  int* cursor   = (int*)alloc((size_t)N * 4);
  int* col_src  = (int*)alloc((size_t)ETOT * 4);
  int* col_dst  = (int*)alloc((size_t)ETOT * 4);
  // xlh: L-side slabs (fp32 for layer 1, fp16 for layers 2/3); xrh: R-side fp32
  float* xlh    = (float*)alloc((size_t)N * 2056 * 4);
  float* xrh    = (float*)alloc((size_t)N * 2056 * 4);
  float* h1     = (float*)alloc((size_t)N * 128 * 4);
  float* h2     = (float*)alloc((size_t)N * 512 * 4);
  float* acc12  = (float*)alloc((size_t)N * 512 * 4);
  bf16_t* xph   = (bf16_t*)alloc((size_t)MPAD * 512 * 2);
  bf16_t* xpl   = (bf16_t*)alloc((size_t)MPAD * 512 * 2);
  // layer-3 group packed W (G=2 heads, Npad=1152, K=512)
  const size_t WPK3 = (size_t)2 * 1152 * 512;
  bf16_t* w3hL  = (bf16_t*)alloc(WPK3 * 2);
  bf16_t* w3lL  = (bf16_t*)alloc(WPK3 * 2);
  bf16_t* w3hR  = (bf16_t*)alloc(WPK3 * 2);
  bf16_t* w3lR  = (bf16_t*)alloc(WPK3 * 2);
  // layer-2 all-heads packed W (Npad=512, K=128)
  const size_t WPK2 = (size_t)HEADS * 512 * 128;
  bf16_t* w2hL  = (bf16_t*)alloc(WPK2 * 2);
  bf16_t* w2lL  = (bf16_t*)alloc(WPK2 * 2);
  bf16_t* w2hR  = (bf16_t*)alloc(WPK2 * 2);
  bf16_t* w2lR  = (bf16_t*)alloc(WPK2 * 2);

  // ---- CSR build (dst-sorted) ----
  init_counts_kernel<<<(N + 255) / 256, 256, 0, stream>>>(counts, N);
  count_kernel<<<(E + 255) / 256, 256, 0, stream>>>(ei + E, counts, E);
  scan_kernel<<<1, 1024, 0, stream>>>(counts, row_ptr, cursor, N);
  scatter_edges_kernel<<<(E + 255) / 256, 256, 0, stream>>>(ei, cursor, col_src, col_dst, E);
  scatter_loops_kernel<<<(N + 255) / 256, 256, 0, stream>>>(cursor, col_src, col_dst, N);

  // ---- layer 1 (fp32 GEMM, 8-head groups of C=1024; fp32 edge) ----
  {
    int C = 128;
    float* acc = acc12;
    for (int g = 0; g < 4; g++) {
      dim3 ggrid(8, MTILES, 2);
      gemm128<<<ggrid, 256, 0, stream>>>(x0, L[0].Wl, L[0].Wr, L[0].bl, L[0].br,
                                         xlh, xrh, N, 4, 1024, HEADS * C, g * 1024);
      edge_fused_multi<1, 32><<<N, 256, 0, stream>>>(row_ptr, col_src, xlh, xrh,
                                                     256, (size_t)32,
                                                     L[0].att + (size_t)(g * 8) * C,
                                                     acc, C, g * 8, 8);
    }
    finalize_kernel<<<((size_t)N * C + 255) / 256, 256, 0, stream>>>(acc, L[0].bias, h1,
                                                                     N * C, C, 1);
  }

  // ---- layer 2 (K=128, C=512, ldh=512; fp16 xl slab; G=4 heads/launch) ----
  {
    int fi = 128, C = 512, ldW = HEADS * C, Npadh = 512, G = 4, ldh = 512;
    float* acc = acc12;
    int total = MPAD * (fi >> 3);
    cvt_pack_kernel<<<(total + 255) / 256, 256, 0, stream>>>(h1, xph, xpl, N, MPAD, fi);
    int wtotal = HEADS * Npadh * (fi >> 3);
    dim3 wgrid((wtotal + 255) / 256, 2);
    pack_w_group_kernel<<<wgrid, 256, 0, stream>>>(L[1].Wl, L[1].Wr, w2hL, w2lL, w2hR, w2lR,
                                                   fi, C, Npadh, ldW, 0, HEADS);
    size_t hstride = (size_t)Npadh * fi;
    size_t strH = (size_t)N * ldh;       // halves per head (L slab)
    size_t strR = (size_t)N * C;         // floats per head (R slab)
    for (int h0 = 0; h0 < HEADS; h0 += G) {
      dim3 ggrid(Npadh / 128, MTILES, 2 * G);
      gemm_mfma_v6<<<ggrid, 256, 0, stream>>>(xph, xpl,
                                              w2hL + h0 * hstride, w2lL + h0 * hstride,
                                              w2hR + h0 * hstride, w2lR + h0 * hstride,
                                              hstride, L[1].bl, L[1].br,
                                              (__half*)xlh, strH, ldh, xrh, strR,
                                              N, fi, C, h0);
      edge_fused_half<1><<<N, 256, 0, stream>>>(row_ptr, col_src,
                                                (const __half*)xlh, xrh,
                                                ldh, strH, C / 4, strR / 4,
                                                L[1].att + (size_t)h0 * C,
                                                acc, C, h0, G);
    }
    finalize_kernel<<<((size_t)N * C + 255) / 256, 256, 0, stream>>>(acc, L[1].bias, h2,
                                                                     N * C, C, 1);
  }

  // ---- layer 3 (K=512, C=1028, ldh=1032; fp16 xl slab; G=2 heads/launch) ----
  {
    int fi = 512, C = 1028, ldW = HEADS * C, Npadh = 1152, G = 2, ldh = 1032;
    float* acc = (float*)d_out;
    int total = MPAD * (fi >> 3);
    cvt_pack_kernel<<<(total + 255) / 256, 256, 0, stream>>>(h2, xph, xpl, N, MPAD, fi);
    size_t hstride = (size_t)Npadh * fi;
    size_t strH = (size_t)N * ldh;       // halves per head (L slab)
    size_t strR = (size_t)N * C;         // floats per head (R slab)
    for (int h0 = 0; h0 < HEADS; h0 += G) {
      int wtotal = G * Npadh * (fi >> 3);
      dim3 wgrid((wtotal + 255) / 256, 2);
      pack_w_group_kernel<<<wgrid, 256, 0, stream>>>(L[2].Wl, L[2].Wr, w3hL, w3lL, w3hR, w3lR,
                                                     fi, C, Npadh, ldW, h0, G);
      dim3 ggrid(Npadh / 128, MTILES, 2 * G);
      gemm_mfma_v6<<<ggrid, 256, 0, stream>>>(xph, xpl, w3hL, w3lL, w3hR, w3lR,
                                              hstride, L[2].bl, L[2].br,
                                              (__half*)xlh, strH, ldh, xrh, strR,
                                              N, fi, C, h0);
      edge_fused_half<3><<<N, 256, 0, stream>>>(row_ptr, col_src,
                                                (const __half*)xlh, xrh,
                                                ldh, strH, C / 4, strR / 4,
                                                L[2].att + (size_t)h0 * C,
                                                acc, C, h0, G);
    }
    finalize_kernel<<<((size_t)N * C + 255) / 256, 256, 0, stream>>>(acc, L[2].bias, (float*)d_out,
                                                                     N * C, C, 0);
  }
}